// Round 1
// baseline (433.052 us; speedup 1.0000x reference)
//
#include <hip/hip_runtime.h>
#include <hip/hip_bf16.h>

// Attention block: x[16,1024,768] -> QKV -> MHA(12 heads, d=64) -> proj.
// All GEMM-shaped compute on bf16 MFMA (16x16x32), softmax in fp32.
// Workspace layout (bytes):
//   xb    @ 0         : bf16 [16384][768]   (x converted)
//   wqkvT @ 25165824  : bf16 [2304][768]    (w_qkv transposed)
//   wprojT@ 28704768  : bf16 [768][768]
//   qb    @ 29884416  : bf16 [B,H,N,D]
//   kb    @ 55050240  : bf16 [B,H,N,D]
//   vT    @ 80216064  : bf16 [B,H,D,N]      (v transposed for PV MFMA B-operand)
//   ao    @ 105381888 : bf16 [16384][768]   (attention output, head-major concat)
// total ~131 MB.

#define EDIM 768
#define NH 12
#define HD 64
#define BB 16
#define SN 1024
#define MTOT (BB*SN)   // 16384

typedef __attribute__((ext_vector_type(8))) short short8;
typedef __attribute__((ext_vector_type(4))) float f32x4;
typedef unsigned short bfr;

__device__ __forceinline__ bfr f2bf(float f) {
    union { float f; unsigned int u; } v; v.f = f;
    unsigned int u = v.u;
    u += 0x7FFFu + ((u >> 16) & 1u);   // round-to-nearest-even
    return (bfr)(u >> 16);
}

// ---------------- convert fp32 -> bf16 (layout-preserving) ----------------
__global__ void k_convert(const float* __restrict__ in, bfr* __restrict__ out, int n4) {
    int i = blockIdx.x * blockDim.x + threadIdx.x;
    if (i >= n4) return;
    float4 v = ((const float4*)in)[i];
    ushort4 o;
    o.x = f2bf(v.x); o.y = f2bf(v.y); o.z = f2bf(v.z); o.w = f2bf(v.w);
    ((ushort4*)out)[i] = o;
}

// ---------------- transpose + convert: in[R][C] fp32 -> out[C][R] bf16 ----------------
__global__ void k_transpose_bf16(const float* __restrict__ in, bfr* __restrict__ out,
                                 int R, int C) {
    __shared__ float tile[32][33];
    int c0 = blockIdx.x * 32, r0 = blockIdx.y * 32;
    int tx = threadIdx.x & 31, ty = threadIdx.x >> 5;   // 256 thr: ty 0..7
    #pragma unroll
    for (int i = 0; i < 32; i += 8)
        tile[ty + i][tx] = in[(size_t)(r0 + ty + i) * C + c0 + tx];
    __syncthreads();
    #pragma unroll
    for (int i = 0; i < 32; i += 8)
        out[(size_t)(c0 + ty + i) * R + r0 + tx] = f2bf(tile[tx][ty + i]);
}

// ---------------- bf16 MFMA GEMM: C[M,N] = A[M,768] @ BT[N,768]^T + bias ----------------
// EPI==0: write fp32 to out (proj). EPI==1: scatter bf16 to qb/kb/vT (QKV).
template <int EPI>
__launch_bounds__(256, 2)
__global__ void k_gemm_bt(const bfr* __restrict__ A, const bfr* __restrict__ BT,
                          const float* __restrict__ bias, float* __restrict__ out,
                          bfr* __restrict__ qb, bfr* __restrict__ kb, bfr* __restrict__ vT) {
    constexpr int LDS_STRIDE = 40;   // 32 + 8 pad (80B rows, 16B aligned, ~2-way banks)
    __shared__ bfr As[128 * LDS_STRIDE];
    __shared__ bfr Bs[128 * LDS_STRIDE];

    const int m0 = blockIdx.y * 128;
    const int n0 = blockIdx.x * 128;
    const int t = threadIdx.x;
    const int lane = t & 63;
    const int wave = t >> 6;
    const int wr = wave >> 1, wc = wave & 1;     // 2x2 wave grid, 64x64 per wave
    const int l15 = lane & 15, quad = lane >> 4;

    f32x4 acc[4][4] = {};

    // staging: 16B chunk per (thread, half): r = t>>2 (0..63), c8 = (t&3)*8
    const int r_a = t >> 2;
    const int c8 = (t & 3) * 8;

    for (int kt = 0; kt < 768; kt += 32) {
        uint4 av0 = *(const uint4*)(A  + (size_t)(m0 + r_a)      * 768 + kt + c8);
        uint4 av1 = *(const uint4*)(A  + (size_t)(m0 + r_a + 64) * 768 + kt + c8);
        uint4 bv0 = *(const uint4*)(BT + (size_t)(n0 + r_a)      * 768 + kt + c8);
        uint4 bv1 = *(const uint4*)(BT + (size_t)(n0 + r_a + 64) * 768 + kt + c8);
        __syncthreads();   // previous iter's fragment reads complete
        *(uint4*)(As + (r_a)      * LDS_STRIDE + c8) = av0;
        *(uint4*)(As + (r_a + 64) * LDS_STRIDE + c8) = av1;
        *(uint4*)(Bs + (r_a)      * LDS_STRIDE + c8) = bv0;
        *(uint4*)(Bs + (r_a + 64) * LDS_STRIDE + c8) = bv1;
        __syncthreads();

        short8 af[4], bf[4];
        #pragma unroll
        for (int rt = 0; rt < 4; rt++)
            af[rt] = *(const short8*)(As + (wr * 64 + rt * 16 + l15) * LDS_STRIDE + quad * 8);
        #pragma unroll
        for (int ct = 0; ct < 4; ct++)
            bf[ct] = *(const short8*)(Bs + (wc * 64 + ct * 16 + l15) * LDS_STRIDE + quad * 8);
        #pragma unroll
        for (int rt = 0; rt < 4; rt++)
            #pragma unroll
            for (int ct = 0; ct < 4; ct++)
                acc[rt][ct] = __builtin_amdgcn_mfma_f32_16x16x32_bf16(af[rt], bf[ct], acc[rt][ct], 0, 0, 0);
    }

    // epilogue: D[row = quad*4+reg][col = l15] per 16x16 tile
    #pragma unroll
    for (int rt = 0; rt < 4; rt++) {
        #pragma unroll
        for (int ct = 0; ct < 4; ct++) {
            const int col = n0 + wc * 64 + ct * 16 + l15;
            const float bv = bias[col];
            #pragma unroll
            for (int reg = 0; reg < 4; reg++) {
                const int m = m0 + wr * 64 + rt * 16 + quad * 4 + reg;
                const float val = acc[rt][ct][reg] + bv;
                if constexpr (EPI == 0) {
                    out[(size_t)m * EDIM + col] = val;
                } else {
                    const int three = col / 768;
                    const int rem = col - three * 768;
                    const int h = rem >> 6, d = rem & 63;
                    const int b = m >> 10, n = m & 1023;
                    const bfr bw = f2bf(val);
                    const size_t bh = (size_t)b * NH + h;
                    if (three == 0)      qb[(bh * SN + n) * HD + d] = bw;
                    else if (three == 1) kb[(bh * SN + n) * HD + d] = bw;
                    else                 vT[(bh * HD + d) * SN + n] = bw;
                }
            }
        }
    }
}

// ---------------- flash attention: per (bh, q-tile of 128), BN=64 kv-tiles ----------------
__launch_bounds__(256, 2)
__global__ void k_attn(const bfr* __restrict__ qb, const bfr* __restrict__ kb,
                       const bfr* __restrict__ vT, bfr* __restrict__ ao) {
    constexpr int LDQ = 80;   // padded row stride (160B, 16B aligned)
    __shared__ bfr Qs[128 * LDQ];
    __shared__ bfr Ks[64 * LDQ];
    __shared__ bfr Vs[64 * LDQ];   // V^T tile: rows=d(64), cols=kv(64)
    __shared__ bfr Ps[128 * LDQ];

    const int q0 = blockIdx.x * 128;
    const int bh = blockIdx.y;
    const int t = threadIdx.x;
    const int lane = t & 63, wave = t >> 6;
    const int l15 = lane & 15, quad = lane >> 4;

    const bfr* qbase = qb + (size_t)bh * SN * HD;
    const bfr* kbase = kb + (size_t)bh * SN * HD;
    const bfr* vbase = vT + (size_t)bh * HD * SN;

    // stage Q tile [128][64] (global region is fully contiguous)
    #pragma unroll
    for (int i = 0; i < 4; i++) {
        int q = t + i * 256;            // chunk of 8 bf16
        int r = q >> 3, cc = (q & 7) * 8;
        *(uint4*)(Qs + r * LDQ + cc) = *(const uint4*)(qbase + (size_t)(q0 + r) * HD + cc);
    }

    f32x4 o_acc[2][4] = {};
    float m_i[2][4], l_i[2][4];
    #pragma unroll
    for (int rt = 0; rt < 2; rt++)
        #pragma unroll
        for (int r = 0; r < 4; r++) { m_i[rt][r] = -__builtin_inff(); l_i[rt][r] = 0.0f; }

    for (int kv0 = 0; kv0 < SN; kv0 += 64) {
        __syncthreads();   // prev PV reads done (also fences Q staging on iter 0)
        #pragma unroll
        for (int i = 0; i < 2; i++) {
            int q = t + i * 256;
            int r = q >> 3, cc = (q & 7) * 8;
            *(uint4*)(Ks + r * LDQ + cc) = *(const uint4*)(kbase + (size_t)(kv0 + r) * HD + cc);
            *(uint4*)(Vs + r * LDQ + cc) = *(const uint4*)(vbase + (size_t)r * SN + kv0 + cc);
        }
        __syncthreads();

        // S = Q K^T (wave handles 32 q-rows x 64 kv-cols)
        f32x4 s[2][4] = {};
        #pragma unroll
        for (int kk = 0; kk < 2; kk++) {
            short8 qf[2], kf[4];
            #pragma unroll
            for (int rt = 0; rt < 2; rt++)
                qf[rt] = *(const short8*)(Qs + (wave * 32 + rt * 16 + l15) * LDQ + kk * 32 + quad * 8);
            #pragma unroll
            for (int ct = 0; ct < 4; ct++)
                kf[ct] = *(const short8*)(Ks + (ct * 16 + l15) * LDQ + kk * 32 + quad * 8);
            #pragma unroll
            for (int rt = 0; rt < 2; rt++)
                #pragma unroll
                for (int ct = 0; ct < 4; ct++)
                    s[rt][ct] = __builtin_amdgcn_mfma_f32_16x16x32_bf16(qf[rt], kf[ct], s[rt][ct], 0, 0, 0);
        }
        #pragma unroll
        for (int rt = 0; rt < 2; rt++)
            #pragma unroll
            for (int ct = 0; ct < 4; ct++)
                s[rt][ct] *= 0.125f;   // D^-0.5

        // online softmax; lane owns rows quad*4+r (rt two 16-blocks)
        #pragma unroll
        for (int rt = 0; rt < 2; rt++) {
            #pragma unroll
            for (int r = 0; r < 4; r++) {
                float mx = -__builtin_inff();
                #pragma unroll
                for (int ct = 0; ct < 4; ct++) mx = fmaxf(mx, s[rt][ct][r]);
                mx = fmaxf(mx, __shfl_xor(mx, 1));
                mx = fmaxf(mx, __shfl_xor(mx, 2));
                mx = fmaxf(mx, __shfl_xor(mx, 4));
                mx = fmaxf(mx, __shfl_xor(mx, 8));
                const float mnew = fmaxf(m_i[rt][r], mx);
                const float alpha = __expf(m_i[rt][r] - mnew);
                m_i[rt][r] = mnew;
                float rsum = 0.f;
                #pragma unroll
                for (int ct = 0; ct < 4; ct++) {
                    float p = __expf(s[rt][ct][r] - mnew);
                    s[rt][ct][r] = p;
                    rsum += p;
                }
                rsum += __shfl_xor(rsum, 1);
                rsum += __shfl_xor(rsum, 2);
                rsum += __shfl_xor(rsum, 4);
                rsum += __shfl_xor(rsum, 8);
                l_i[rt][r] = l_i[rt][r] * alpha + rsum;
                #pragma unroll
                for (int ct = 0; ct < 4; ct++) o_acc[rt][ct][r] *= alpha;
            }
        }

        // P: C-layout -> LDS (row = quad*4+r), read back in A-layout for PV
        #pragma unroll
        for (int rt = 0; rt < 2; rt++)
            #pragma unroll
            for (int ct = 0; ct < 4; ct++)
                #pragma unroll
                for (int r = 0; r < 4; r++)
                    Ps[(wave * 32 + rt * 16 + quad * 4 + r) * LDQ + ct * 16 + l15] = f2bf(s[rt][ct][r]);
        __syncthreads();

        // O += P @ V  (B-operand from V^T rows = contiguous)
        #pragma unroll
        for (int kk = 0; kk < 2; kk++) {
            short8 pf[2], vf[4];
            #pragma unroll
            for (int rt = 0; rt < 2; rt++)
                pf[rt] = *(const short8*)(Ps + (wave * 32 + rt * 16 + l15) * LDQ + kk * 32 + quad * 8);
            #pragma unroll
            for (int ct = 0; ct < 4; ct++)
                vf[ct] = *(const short8*)(Vs + (ct * 16 + l15) * LDQ + kk * 32 + quad * 8);
            #pragma unroll
            for (int rt = 0; rt < 2; rt++)
                #pragma unroll
                for (int ct = 0; ct < 4; ct++)
                    o_acc[rt][ct] = __builtin_amdgcn_mfma_f32_16x16x32_bf16(pf[rt], vf[ct], o_acc[rt][ct], 0, 0, 0);
        }
    }

    // normalize + write bf16 to ao[b, n, h*64+d]
    const int b = bh / NH, h = bh % NH;
    #pragma unroll
    for (int rt = 0; rt < 2; rt++) {
        #pragma unroll
        for (int r = 0; r < 4; r++) {
            const float inv = 1.0f / l_i[rt][r];
            const int n = q0 + wave * 32 + rt * 16 + quad * 4 + r;
            #pragma unroll
            for (int ct = 0; ct < 4; ct++) {
                const int d = ct * 16 + l15;
                ao[((size_t)b * SN + n) * EDIM + h * HD + d] = f2bf(o_acc[rt][ct][r] * inv);
            }
        }
    }
}

extern "C" void kernel_launch(void* const* d_in, const int* in_sizes, int n_in,
                              void* d_out, int out_size, void* d_ws, size_t ws_size,
                              hipStream_t stream) {
    const float* x      = (const float*)d_in[0];
    const float* w_qkv  = (const float*)d_in[1];
    const float* b_qkv  = (const float*)d_in[2];
    const float* w_proj = (const float*)d_in[3];
    const float* b_proj = (const float*)d_in[4];

    char* ws = (char*)d_ws;
    bfr* xb     = (bfr*)(ws + 0);
    bfr* wqkvT  = (bfr*)(ws + 25165824);
    bfr* wprojT = (bfr*)(ws + 28704768);
    bfr* qb     = (bfr*)(ws + 29884416);
    bfr* kb     = (bfr*)(ws + 55050240);
    bfr* vT     = (bfr*)(ws + 80216064);
    bfr* ao     = (bfr*)(ws + 105381888);

    // 1) x -> bf16
    k_convert<<<12288, 256, 0, stream>>>(x, xb, (MTOT * EDIM) / 4);
    // 2) weight transposes -> bf16
    k_transpose_bf16<<<dim3(2304 / 32, 768 / 32), 256, 0, stream>>>(w_qkv, wqkvT, 768, 2304);
    k_transpose_bf16<<<dim3(768 / 32, 768 / 32), 256, 0, stream>>>(w_proj, wprojT, 768, 768);
    // 3) QKV GEMM + bias, scatter to q/k/vT
    k_gemm_bt<1><<<dim3(2304 / 128, MTOT / 128), 256, 0, stream>>>(
        xb, wqkvT, b_qkv, nullptr, qb, kb, vT);
    // 4) flash attention
    k_attn<<<dim3(SN / 128, BB * NH), 256, 0, stream>>>(qb, kb, vT, ao);
    // 5) output projection + bias -> fp32 d_out
    k_gemm_bt<0><<<dim3(768 / 128, MTOT / 128), 256, 0, stream>>>(
        ao, wprojT, b_proj, (float*)d_out, nullptr, nullptr, nullptr);
}